// Round 4
// baseline (351.894 us; speedup 1.0000x reference)
//
#include <hip/hip_runtime.h>
#include <hip/hip_bf16.h>

typedef __bf16 bf16_t;
typedef __bf16 bf16x4 __attribute__((ext_vector_type(4)));
typedef __bf16 bf16x8 __attribute__((ext_vector_type(8)));
typedef float f32x4 __attribute__((ext_vector_type(4)));

#define AS1(p) ((const __attribute__((address_space(1))) void*)(p))
#define AS3(p) ((__attribute__((address_space(3))) void*)(p))

__device__ __forceinline__ f32x4 mfma16(bf16x8 a, bf16x8 b, f32x4 c) {
  return __builtin_amdgcn_mfma_f32_16x16x32_bf16(a, b, c, 0, 0, 0);
}

__global__ void cvt_f32_to_bf16(const float* __restrict__ in, bf16_t* __restrict__ out, int n) {
  int i = (blockIdx.x * 256 + threadIdx.x) * 4;
  if (i >= n) return;
  float4 v = *(const float4*)(in + i);
  bf16x4 o = {(bf16_t)v.x, (bf16_t)v.y, (bf16_t)v.z, (bf16_t)v.w};
  *(bf16x4*)(out + i) = o;
}

// Tiled transpose+cast: Wt[n*K+k] = (bf16)W[k*N+n]
__global__ void transpose_cvt_t(const float* __restrict__ W, bf16_t* __restrict__ Wt,
                                int K, int N) {
  __shared__ float t[64][65];
  const int n0 = blockIdx.x * 64, k0 = blockIdx.y * 64;
  const int tx = threadIdx.x & 63, ty = threadIdx.x >> 6;
#pragma unroll
  for (int i = 0; i < 16; ++i)
    t[ty * 16 + i][tx] = W[(size_t)(k0 + ty * 16 + i) * N + n0 + tx];
  __syncthreads();
#pragma unroll
  for (int i = 0; i < 16; ++i)
    Wt[(size_t)(n0 + ty * 16 + i) * K + k0 + tx] = (bf16_t)t[tx][ty * 16 + i];
}

__global__ void pack_bias_kv(const float* __restrict__ bk, const float* __restrict__ bv,
                             float* __restrict__ bkv) {
  int i = threadIdx.x;
  bkv[i] = (i < 64) ? bk[i] : bv[i - 64];
}

// VtG[(b*64+d)*2048 + s] = KVb[(b*2048+s)*128 + 64 + d]
__global__ void transpose_v(const bf16_t* __restrict__ KVb, bf16_t* __restrict__ VtG) {
  __shared__ bf16_t t[64][72];
  const int s0 = blockIdx.x * 64, b = blockIdx.y;
  const int tx = threadIdx.x & 63, ty = threadIdx.x >> 6;
#pragma unroll
  for (int i = 0; i < 16; ++i)
    t[ty * 16 + i][tx] = KVb[(size_t)(b * 2048 + s0 + ty * 16 + i) * 128 + 64 + tx];
  __syncthreads();
#pragma unroll
  for (int i = 0; i < 16; ++i)
    VtG[(size_t)(b * 64 + ty * 16 + i) * 2048 + s0 + tx] = t[tx][ty * 16 + i];
}

// C[M,N] = A[M,K] @ Bt[N,K]^T + bias ; 128x128 tile, BK=32, 4 waves.
__global__ __launch_bounds__(256, 2)
void gemm_nt_bias_b16(const bf16_t* __restrict__ A, const bf16_t* __restrict__ Bt,
                      const float* __restrict__ bias, bf16_t* __restrict__ C,
                      int M, int N, int K) {
  __shared__ __align__(16) bf16_t As[128 * 32];
  __shared__ __align__(16) bf16_t Bs[128 * 32];
  const int tid = threadIdx.x;
  const int w = tid >> 6, l = tid & 63;
  const int l15 = l & 15, q = l >> 4;
  const int m0 = blockIdx.x * 128, n0 = blockIdx.y * 128;
  const int mw = (w >> 1) * 64, nw = (w & 1) * 64;
  f32x4 acc[4][4] = {};
  const int kb = (l & 3) * 8;
  int rA[2], rB[2];
#pragma unroll
  for (int i = 0; i < 2; ++i) {
    int row = (i * 4 + w) * 16 + (l >> 2);
    rA[i] = m0 + row;
    int rb = n0 + row; if (rb >= N) rb = N - 1;
    rB[i] = rb;
  }
  for (int k0 = 0; k0 < K; k0 += 32) {
#pragma unroll
    for (int i = 0; i < 2; ++i) {
      int sg = i * 4 + w;
      __builtin_amdgcn_global_load_lds(AS1(A + (size_t)rA[i] * K + k0 + kb),
                                       AS3(As + sg * 512), 16, 0, 0);
      __builtin_amdgcn_global_load_lds(AS1(Bt + (size_t)rB[i] * K + k0 + kb),
                                       AS3(Bs + sg * 512), 16, 0, 0);
    }
    __syncthreads();
    bf16x8 af[4], bfr[4];
#pragma unroll
    for (int mi = 0; mi < 4; ++mi)
      af[mi] = *(const bf16x8*)(As + (mw + mi * 16 + l15) * 32 + q * 8);
#pragma unroll
    for (int ni = 0; ni < 4; ++ni)
      bfr[ni] = *(const bf16x8*)(Bs + (nw + ni * 16 + l15) * 32 + q * 8);
#pragma unroll
    for (int mi = 0; mi < 4; ++mi)
#pragma unroll
      for (int ni = 0; ni < 4; ++ni)
        acc[mi][ni] = mfma16(af[mi], bfr[ni], acc[mi][ni]);
    __syncthreads();
  }
#pragma unroll
  for (int ni = 0; ni < 4; ++ni) {
    int col = n0 + nw + ni * 16 + l15;
    if (col >= N) continue;
    float bv = bias[col];
#pragma unroll
    for (int mi = 0; mi < 4; ++mi)
#pragma unroll
      for (int r = 0; r < 4; ++r) {
        int row = m0 + mw + mi * 16 + q * 4 + r;
        C[(size_t)row * N + col] = (bf16_t)(acc[mi][ni][r] + bv);
      }
  }
}

__global__ __launch_bounds__(256, 2)
void gemm_nt_bias_f32(const bf16_t* __restrict__ A, const bf16_t* __restrict__ Bt,
                      const float* __restrict__ bias, float* __restrict__ C,
                      int M, int N, int K) {
  __shared__ __align__(16) bf16_t As[128 * 32];
  __shared__ __align__(16) bf16_t Bs[128 * 32];
  const int tid = threadIdx.x;
  const int w = tid >> 6, l = tid & 63;
  const int l15 = l & 15, q = l >> 4;
  const int m0 = blockIdx.x * 128, n0 = blockIdx.y * 128;
  const int mw = (w >> 1) * 64, nw = (w & 1) * 64;
  f32x4 acc[4][4] = {};
  const int kb = (l & 3) * 8;
  int rA[2], rB[2];
#pragma unroll
  for (int i = 0; i < 2; ++i) {
    int row = (i * 4 + w) * 16 + (l >> 2);
    rA[i] = m0 + row;
    int rb = n0 + row; if (rb >= N) rb = N - 1;
    rB[i] = rb;
  }
  for (int k0 = 0; k0 < K; k0 += 32) {
#pragma unroll
    for (int i = 0; i < 2; ++i) {
      int sg = i * 4 + w;
      __builtin_amdgcn_global_load_lds(AS1(A + (size_t)rA[i] * K + k0 + kb),
                                       AS3(As + sg * 512), 16, 0, 0);
      __builtin_amdgcn_global_load_lds(AS1(Bt + (size_t)rB[i] * K + k0 + kb),
                                       AS3(Bs + sg * 512), 16, 0, 0);
    }
    __syncthreads();
    bf16x8 af[4], bfr[4];
#pragma unroll
    for (int mi = 0; mi < 4; ++mi)
      af[mi] = *(const bf16x8*)(As + (mw + mi * 16 + l15) * 32 + q * 8);
#pragma unroll
    for (int ni = 0; ni < 4; ++ni)
      bfr[ni] = *(const bf16x8*)(Bs + (nw + ni * 16 + l15) * 32 + q * 8);
#pragma unroll
    for (int mi = 0; mi < 4; ++mi)
#pragma unroll
      for (int ni = 0; ni < 4; ++ni)
        acc[mi][ni] = mfma16(af[mi], bfr[ni], acc[mi][ni]);
    __syncthreads();
  }
#pragma unroll
  for (int ni = 0; ni < 4; ++ni) {
    int col = n0 + nw + ni * 16 + l15;
    if (col >= N) continue;
    float bv = bias[col];
#pragma unroll
    for (int mi = 0; mi < 4; ++mi)
#pragma unroll
      for (int r = 0; r < 4; ++r) {
        int row = m0 + mw + mi * 16 + q * 4 + r;
        C[(size_t)row * N + col] = acc[mi][ni][r] + bv;
      }
  }
}

// ---- MQA flash v7: output-split waves, 16 waves/CU target ----
// v6 post-mortem: occupancy stuck at 19% because grid (1024 blk x 2 waves)
// + 35.8 KB LDS (the f32 combine buffer) cap residency at 8 waves/CU; with
// only 2 waves/SIMD the per-step chain (L2 load -> MFMA -> exp -> LDS P
// roundtrip -> MFMA) can't be hidden (MfmaUtil 18 + VALUBusy 30).
// Fix: split the OUTPUT instead of kt. Each wave owns 32 queries x full kt
// range: no combine at all, LDS = 9 KB (P stripes only), 2048 blocks x 2
// waves = 16 waves/CU if VGPR <= 128. Register budget (v5 lesson): K frags
// per-mk-half (16), S halved (16), V hoisted (32), o 32, qf 16 -> peak ~122.
// K/V direct from L2 (b in low bits: ~1 MB working set per XCD L2); both
// waves of a block read the same K/V tile -> second wave L1-hits.
// Heavy-first (qt=31 first) for balanced drain; light blocks fill the tail.
__global__ __launch_bounds__(128, 4)
void mqa_attn7(const bf16_t* __restrict__ Qb, const bf16_t* __restrict__ KVb,
               const bf16_t* __restrict__ VtG, bf16_t* __restrict__ AO) {
  __shared__ __align__(16) bf16_t Ps[2][2][16 * 72];  // 9 KB: [wave][nq] stripes
  const int u = blockIdx.x;
  const int b = u & 3;                 // low bits -> batch pinned to XCD L2
  const int h = (u >> 2) & 15;
  const int qt = 31 - (u >> 6);        // heavy blocks dispatched first
  const int w = threadIdx.x >> 6, l = threadIdx.x & 63;
  const int l15 = l & 15, q = l >> 4;

  // Q B-fragments: queries qt*64 + w*32 + nq*16 + l15 (resident all loop)
  bf16x8 qf0[2], qf1[2];
#pragma unroll
  for (int nq = 0; nq < 2; ++nq) {
    const bf16_t* qp =
        Qb + (size_t)(b * 2048 + qt * 64 + w * 32 + nq * 16 + l15) * 1024 + h * 64 + q * 8;
    qf0[nq] = *(const bf16x8*)qp;
    qf1[nq] = *(const bf16x8*)(qp + 32);
  }

  f32x4 o[4][2] = {};                  // o[md][nq] = O^T accum (32 queries)
  float rs[2] = {0.f, 0.f};
  const bf16_t* kbase = KVb + (size_t)b * 2048 * 128;   // K = cols 0..63, stride 128
  const bf16_t* vbase = VtG + (size_t)b * 64 * 2048;
  const float c1 = 0.18033688f;        // log2(e)/8
  const int qloc = w * 32 + l15;       // + nq*16 at use

  for (int kt = 0; kt <= qt; ++kt) {
    // V^T fragments issued first: latency hides under QK + softmax
    bf16x8 va0[4], va1[4];
#pragma unroll
    for (int md = 0; md < 4; ++md) {
      const bf16_t* vr = vbase + (size_t)(md * 16 + l15) * 2048 + kt * 64;
      va0[md] = *(const bf16x8*)(vr + q * 8);
      va1[md] = *(const bf16x8*)(vr + 32 + q * 8);
    }
    const bf16_t* kb = kbase + (size_t)kt * 64 * 128;
    const bool diag = (kt == qt);
    // QK^T + softmax in two mk-halves: bounds ka (16) and s (16) registers
#pragma unroll
    for (int mh = 0; mh < 2; ++mh) {
      bf16x8 ka0[2], ka1[2];
#pragma unroll
      for (int mk2 = 0; mk2 < 2; ++mk2) {
        const bf16_t* kr = kb + ((mh * 2 + mk2) * 16 + l15) * 128;
        ka0[mk2] = *(const bf16x8*)(kr + q * 8);
        ka1[mk2] = *(const bf16x8*)(kr + 32 + q * 8);
      }
      f32x4 s2[2][2];
      __builtin_amdgcn_s_setprio(1);
#pragma unroll
      for (int mk2 = 0; mk2 < 2; ++mk2)
#pragma unroll
        for (int nq = 0; nq < 2; ++nq) {
          f32x4 t = {0.f, 0.f, 0.f, 0.f};
          t = mfma16(ka0[mk2], qf0[nq], t);
          t = mfma16(ka1[mk2], qf1[nq], t);
          s2[mk2][nq] = t;
        }
      __builtin_amdgcn_s_setprio(0);
#pragma unroll
      for (int nq = 0; nq < 2; ++nq)
#pragma unroll
        for (int mk2 = 0; mk2 < 2; ++mk2) {
          const int mk = mh * 2 + mk2;
          bf16x4 pk;
#pragma unroll
          for (int r = 0; r < 4; ++r) {
            float pv = __builtin_amdgcn_exp2f(s2[mk2][nq][r] * c1 - 16.0f);
            if (diag && (mk * 16 + q * 4 + r) > (qloc + nq * 16)) pv = 0.f;
            rs[nq] += pv;
            pk[r] = (bf16_t)pv;
          }
          *(bf16x4*)(&Ps[w][nq][0] + l15 * 72 + mk * 16 + q * 4) = pk;
        }
    }
    // O^T += V^T * P  (wave-private stripes; in-wave lgkmcnt ordering)
#pragma unroll
    for (int nq = 0; nq < 2; ++nq) {
      bf16x8 pb0 = *(const bf16x8*)(&Ps[w][nq][0] + l15 * 72 + q * 8);
      bf16x8 pb1 = *(const bf16x8*)(&Ps[w][nq][0] + l15 * 72 + 32 + q * 8);
      __builtin_amdgcn_s_setprio(1);
#pragma unroll
      for (int md = 0; md < 4; ++md) {
        o[md][nq] = mfma16(va0[md], pb0, o[md][nq]);
        o[md][nq] = mfma16(va1[md], pb1, o[md][nq]);
      }
      __builtin_amdgcn_s_setprio(0);
    }
  }

  // row-sum reduction across the 4 q-lane groups of each query column
#pragma unroll
  for (int nq = 0; nq < 2; ++nq) {
    rs[nq] += __shfl_xor(rs[nq], 16);
    rs[nq] += __shfl_xor(rs[nq], 32);
  }
  float inv[2] = {1.f / rs[0], 1.f / rs[1]};
#pragma unroll
  for (int md = 0; md < 4; ++md)
#pragma unroll
    for (int nq = 0; nq < 2; ++nq) {
      bf16x4 ov = {(bf16_t)(o[md][nq][0] * inv[nq]), (bf16_t)(o[md][nq][1] * inv[nq]),
                   (bf16_t)(o[md][nq][2] * inv[nq]), (bf16_t)(o[md][nq][3] * inv[nq])};
      *(bf16x4*)(AO + (size_t)(b * 2048 + qt * 64 + w * 32 + nq * 16 + l15) * 1024 +
                 h * 64 + md * 16 + q * 4) = ov;
    }
}

extern "C" void kernel_launch(void* const* d_in, const int* in_sizes, int n_in,
                              void* d_out, int out_size, void* d_ws, size_t ws_size,
                              hipStream_t stream) {
  (void)in_sizes; (void)n_in; (void)out_size; (void)ws_size;
  const int BS = 8192;  // B*S
  const float* x  = (const float*)d_in[0];
  const float* Wq = (const float*)d_in[1];
  const float* bq = (const float*)d_in[2];
  const float* Wk = (const float*)d_in[3];
  const float* bk = (const float*)d_in[4];
  const float* Wv = (const float*)d_in[5];
  const float* bv = (const float*)d_in[6];
  const float* Wo = (const float*)d_in[7];
  const float* bo = (const float*)d_in[8];
  float* out = (float*)d_out;

  bf16_t* p = (bf16_t*)d_ws;
  bf16_t* WqT  = p; p += 1024 * 1024;
  bf16_t* WkvT = p; p += 128 * 1024;   // rows 0-63 = Wk^T, 64-127 = Wv^T
  bf16_t* WoT  = p; p += 1024 * 1024;
  bf16_t* xb   = p; p += (size_t)BS * 1024;
  bf16_t* Qb   = p; p += (size_t)BS * 1024;
  bf16_t* KVb  = p; p += (size_t)BS * 128;   // cols 0-63 = K, 64-127 = V
  float*  bkv  = (float*)p; p += 256;        // 128 f32
  bf16_t* AO  = xb;   // x dead after projections
  bf16_t* VtG = WqT;  // Wq dead after Q projection

  cvt_f32_to_bf16<<<(BS * 1024 / 4 + 255) / 256, 256, 0, stream>>>(x, xb, BS * 1024);
  transpose_cvt_t<<<dim3(16, 16), 256, 0, stream>>>(Wq, WqT, 1024, 1024);
  transpose_cvt_t<<<dim3(1, 16), 256, 0, stream>>>(Wk, WkvT, 1024, 64);
  transpose_cvt_t<<<dim3(1, 16), 256, 0, stream>>>(Wv, WkvT + 64 * 1024, 1024, 64);
  transpose_cvt_t<<<dim3(16, 16), 256, 0, stream>>>(Wo, WoT, 1024, 1024);
  pack_bias_kv<<<1, 128, 0, stream>>>(bk, bv, bkv);

  gemm_nt_bias_b16<<<dim3(BS / 128, 8), 256, 0, stream>>>(xb, WqT, bq, Qb, BS, 1024, 1024);
  // fused K+V projection: one N=128 dispatch instead of two N=64 (same per-block
  // cost: 64 blocks x full K loop -> halves projection time)
  gemm_nt_bias_b16<<<dim3(BS / 128, 1), 256, 0, stream>>>(xb, WkvT, bkv, KVb, BS, 128, 1024);

  transpose_v<<<dim3(32, 4), 256, 0, stream>>>(KVb, VtG);

  mqa_attn7<<<dim3(2048), 128, 0, stream>>>(Qb, KVb, VtG, AO);

  gemm_nt_bias_f32<<<dim3(BS / 128, 8), 256, 0, stream>>>(AO, WoT, bo, out, BS, 1024, 1024);
}

// Round 5
// 321.108 us; speedup vs baseline: 1.0959x; 1.0959x over previous
//
#include <hip/hip_runtime.h>
#include <hip/hip_bf16.h>

typedef __bf16 bf16_t;
typedef __bf16 bf16x4 __attribute__((ext_vector_type(4)));
typedef __bf16 bf16x8 __attribute__((ext_vector_type(8)));
typedef float f32x4 __attribute__((ext_vector_type(4)));

#define AS1(p) ((const __attribute__((address_space(1))) void*)(p))
#define AS3(p) ((__attribute__((address_space(3))) void*)(p))

__device__ __forceinline__ f32x4 mfma16(bf16x8 a, bf16x8 b, f32x4 c) {
  return __builtin_amdgcn_mfma_f32_16x16x32_bf16(a, b, c, 0, 0, 0);
}

__global__ void cvt_f32_to_bf16(const float* __restrict__ in, bf16_t* __restrict__ out, int n) {
  int i = (blockIdx.x * 256 + threadIdx.x) * 4;
  if (i >= n) return;
  float4 v = *(const float4*)(in + i);
  bf16x4 o = {(bf16_t)v.x, (bf16_t)v.y, (bf16_t)v.z, (bf16_t)v.w};
  *(bf16x4*)(out + i) = o;
}

// Tiled transpose+cast: Wt[n*K+k] = (bf16)W[k*N+n]
__global__ void transpose_cvt_t(const float* __restrict__ W, bf16_t* __restrict__ Wt,
                                int K, int N) {
  __shared__ float t[64][65];
  const int n0 = blockIdx.x * 64, k0 = blockIdx.y * 64;
  const int tx = threadIdx.x & 63, ty = threadIdx.x >> 6;
#pragma unroll
  for (int i = 0; i < 16; ++i)
    t[ty * 16 + i][tx] = W[(size_t)(k0 + ty * 16 + i) * N + n0 + tx];
  __syncthreads();
#pragma unroll
  for (int i = 0; i < 16; ++i)
    Wt[(size_t)(n0 + ty * 16 + i) * K + k0 + tx] = (bf16_t)t[tx][ty * 16 + i];
}

__global__ void pack_bias_kv(const float* __restrict__ bk, const float* __restrict__ bv,
                             float* __restrict__ bkv) {
  int i = threadIdx.x;
  bkv[i] = (i < 64) ? bk[i] : bv[i - 64];
}

// VtG[(b*64+d)*2048 + s] = KVb[(b*2048+s)*128 + 64 + d]
__global__ void transpose_v(const bf16_t* __restrict__ KVb, bf16_t* __restrict__ VtG) {
  __shared__ bf16_t t[64][72];
  const int s0 = blockIdx.x * 64, b = blockIdx.y;
  const int tx = threadIdx.x & 63, ty = threadIdx.x >> 6;
#pragma unroll
  for (int i = 0; i < 16; ++i)
    t[ty * 16 + i][tx] = KVb[(size_t)(b * 2048 + s0 + ty * 16 + i) * 128 + 64 + tx];
  __syncthreads();
#pragma unroll
  for (int i = 0; i < 16; ++i)
    VtG[(size_t)(b * 64 + ty * 16 + i) * 2048 + s0 + tx] = t[tx][ty * 16 + i];
}

// C[M,N] = A[M,K] @ Bt[N,K]^T + bias ; 128x128 tile, BK=32, 4 waves.
__global__ __launch_bounds__(256, 2)
void gemm_nt_bias_b16(const bf16_t* __restrict__ A, const bf16_t* __restrict__ Bt,
                      const float* __restrict__ bias, bf16_t* __restrict__ C,
                      int M, int N, int K) {
  __shared__ __align__(16) bf16_t As[128 * 32];
  __shared__ __align__(16) bf16_t Bs[128 * 32];
  const int tid = threadIdx.x;
  const int w = tid >> 6, l = tid & 63;
  const int l15 = l & 15, q = l >> 4;
  const int m0 = blockIdx.x * 128, n0 = blockIdx.y * 128;
  const int mw = (w >> 1) * 64, nw = (w & 1) * 64;
  f32x4 acc[4][4] = {};
  const int kb = (l & 3) * 8;
  int rA[2], rB[2];
#pragma unroll
  for (int i = 0; i < 2; ++i) {
    int row = (i * 4 + w) * 16 + (l >> 2);
    rA[i] = m0 + row;
    int rb = n0 + row; if (rb >= N) rb = N - 1;
    rB[i] = rb;
  }
  for (int k0 = 0; k0 < K; k0 += 32) {
#pragma unroll
    for (int i = 0; i < 2; ++i) {
      int sg = i * 4 + w;
      __builtin_amdgcn_global_load_lds(AS1(A + (size_t)rA[i] * K + k0 + kb),
                                       AS3(As + sg * 512), 16, 0, 0);
      __builtin_amdgcn_global_load_lds(AS1(Bt + (size_t)rB[i] * K + k0 + kb),
                                       AS3(Bs + sg * 512), 16, 0, 0);
    }
    __syncthreads();
    bf16x8 af[4], bfr[4];
#pragma unroll
    for (int mi = 0; mi < 4; ++mi)
      af[mi] = *(const bf16x8*)(As + (mw + mi * 16 + l15) * 32 + q * 8);
#pragma unroll
    for (int ni = 0; ni < 4; ++ni)
      bfr[ni] = *(const bf16x8*)(Bs + (nw + ni * 16 + l15) * 32 + q * 8);
#pragma unroll
    for (int mi = 0; mi < 4; ++mi)
#pragma unroll
      for (int ni = 0; ni < 4; ++ni)
        acc[mi][ni] = mfma16(af[mi], bfr[ni], acc[mi][ni]);
    __syncthreads();
  }
#pragma unroll
  for (int ni = 0; ni < 4; ++ni) {
    int col = n0 + nw + ni * 16 + l15;
    if (col >= N) continue;
    float bv = bias[col];
#pragma unroll
    for (int mi = 0; mi < 4; ++mi)
#pragma unroll
      for (int r = 0; r < 4; ++r) {
        int row = m0 + mw + mi * 16 + q * 4 + r;
        C[(size_t)row * N + col] = (bf16_t)(acc[mi][ni][r] + bv);
      }
  }
}

__global__ __launch_bounds__(256, 2)
void gemm_nt_bias_f32(const bf16_t* __restrict__ A, const bf16_t* __restrict__ Bt,
                      const float* __restrict__ bias, float* __restrict__ C,
                      int M, int N, int K) {
  __shared__ __align__(16) bf16_t As[128 * 32];
  __shared__ __align__(16) bf16_t Bs[128 * 32];
  const int tid = threadIdx.x;
  const int w = tid >> 6, l = tid & 63;
  const int l15 = l & 15, q = l >> 4;
  const int m0 = blockIdx.x * 128, n0 = blockIdx.y * 128;
  const int mw = (w >> 1) * 64, nw = (w & 1) * 64;
  f32x4 acc[4][4] = {};
  const int kb = (l & 3) * 8;
  int rA[2], rB[2];
#pragma unroll
  for (int i = 0; i < 2; ++i) {
    int row = (i * 4 + w) * 16 + (l >> 2);
    rA[i] = m0 + row;
    int rb = n0 + row; if (rb >= N) rb = N - 1;
    rB[i] = rb;
  }
  for (int k0 = 0; k0 < K; k0 += 32) {
#pragma unroll
    for (int i = 0; i < 2; ++i) {
      int sg = i * 4 + w;
      __builtin_amdgcn_global_load_lds(AS1(A + (size_t)rA[i] * K + k0 + kb),
                                       AS3(As + sg * 512), 16, 0, 0);
      __builtin_amdgcn_global_load_lds(AS1(Bt + (size_t)rB[i] * K + k0 + kb),
                                       AS3(Bs + sg * 512), 16, 0, 0);
    }
    __syncthreads();
    bf16x8 af[4], bfr[4];
#pragma unroll
    for (int mi = 0; mi < 4; ++mi)
      af[mi] = *(const bf16x8*)(As + (mw + mi * 16 + l15) * 32 + q * 8);
#pragma unroll
    for (int ni = 0; ni < 4; ++ni)
      bfr[ni] = *(const bf16x8*)(Bs + (nw + ni * 16 + l15) * 32 + q * 8);
#pragma unroll
    for (int mi = 0; mi < 4; ++mi)
#pragma unroll
      for (int ni = 0; ni < 4; ++ni)
        acc[mi][ni] = mfma16(af[mi], bfr[ni], acc[mi][ni]);
    __syncthreads();
  }
#pragma unroll
  for (int ni = 0; ni < 4; ++ni) {
    int col = n0 + nw + ni * 16 + l15;
    if (col >= N) continue;
    float bv = bias[col];
#pragma unroll
    for (int mi = 0; mi < 4; ++mi)
#pragma unroll
      for (int r = 0; r < 4; ++r) {
        int row = m0 + mw + mi * 16 + q * 4 + r;
        C[(size_t)row * N + col] = acc[mi][ni][r] + bv;
      }
  }
}

// ---- MQA flash v8: v7 structure, launch_bounds(128,2) ----
// v7 post-mortem: min-waves=4 in launch_bounds CLAMPS the allocator to 64
// VGPRs on this toolchain (observed twice: v5 (64,4)->64+spill, v7
// (128,4)->64+spill; v3 (256,2)->116, v6 (128,2)->104 are unclamped).
// The output-split structure itself did what was predicted (occupancy
// 19->31% even while spilling). Fix: request min 2 waves only -- actual
// residency is set by the REAL VGPR count (~100-125 <= 128 -> HW allows
// 4 waves/SIMD), LDS 9 KB allows 16 blocks/CU, grid 2048 = 8 blocks/CU
// -> 16 waves/CU, 2x v6. Everything else identical to v7.
__global__ __launch_bounds__(128, 2)
void mqa_attn8(const bf16_t* __restrict__ Qb, const bf16_t* __restrict__ KVb,
               const bf16_t* __restrict__ VtG, bf16_t* __restrict__ AO) {
  __shared__ __align__(16) bf16_t Ps[2][2][16 * 72];  // 9 KB: [wave][nq] stripes
  const int u = blockIdx.x;
  const int b = u & 3;                 // low bits -> batch pinned to XCD L2
  const int h = (u >> 2) & 15;
  const int qt = 31 - (u >> 6);        // heavy blocks dispatched first
  const int w = threadIdx.x >> 6, l = threadIdx.x & 63;
  const int l15 = l & 15, q = l >> 4;

  // Q B-fragments: queries qt*64 + w*32 + nq*16 + l15 (resident all loop)
  bf16x8 qf0[2], qf1[2];
#pragma unroll
  for (int nq = 0; nq < 2; ++nq) {
    const bf16_t* qp =
        Qb + (size_t)(b * 2048 + qt * 64 + w * 32 + nq * 16 + l15) * 1024 + h * 64 + q * 8;
    qf0[nq] = *(const bf16x8*)qp;
    qf1[nq] = *(const bf16x8*)(qp + 32);
  }

  f32x4 o[4][2] = {};                  // o[md][nq] = O^T accum (32 queries)
  float rs[2] = {0.f, 0.f};
  const bf16_t* kbase = KVb + (size_t)b * 2048 * 128;   // K = cols 0..63, stride 128
  const bf16_t* vbase = VtG + (size_t)b * 64 * 2048;
  const float c1 = 0.18033688f;        // log2(e)/8
  const int qloc = w * 32 + l15;       // + nq*16 at use

  for (int kt = 0; kt <= qt; ++kt) {
    // V^T fragments issued first: latency hides under QK + softmax
    bf16x8 va0[4], va1[4];
#pragma unroll
    for (int md = 0; md < 4; ++md) {
      const bf16_t* vr = vbase + (size_t)(md * 16 + l15) * 2048 + kt * 64;
      va0[md] = *(const bf16x8*)(vr + q * 8);
      va1[md] = *(const bf16x8*)(vr + 32 + q * 8);
    }
    const bf16_t* kb = kbase + (size_t)kt * 64 * 128;
    const bool diag = (kt == qt);
    // QK^T + softmax in two mk-halves: bounds ka (16) and s (16) registers
#pragma unroll
    for (int mh = 0; mh < 2; ++mh) {
      bf16x8 ka0[2], ka1[2];
#pragma unroll
      for (int mk2 = 0; mk2 < 2; ++mk2) {
        const bf16_t* kr = kb + ((mh * 2 + mk2) * 16 + l15) * 128;
        ka0[mk2] = *(const bf16x8*)(kr + q * 8);
        ka1[mk2] = *(const bf16x8*)(kr + 32 + q * 8);
      }
      f32x4 s2[2][2];
      __builtin_amdgcn_s_setprio(1);
#pragma unroll
      for (int mk2 = 0; mk2 < 2; ++mk2)
#pragma unroll
        for (int nq = 0; nq < 2; ++nq) {
          f32x4 t = {0.f, 0.f, 0.f, 0.f};
          t = mfma16(ka0[mk2], qf0[nq], t);
          t = mfma16(ka1[mk2], qf1[nq], t);
          s2[mk2][nq] = t;
        }
      __builtin_amdgcn_s_setprio(0);
#pragma unroll
      for (int nq = 0; nq < 2; ++nq)
#pragma unroll
        for (int mk2 = 0; mk2 < 2; ++mk2) {
          const int mk = mh * 2 + mk2;
          bf16x4 pk;
#pragma unroll
          for (int r = 0; r < 4; ++r) {
            float pv = __builtin_amdgcn_exp2f(s2[mk2][nq][r] * c1 - 16.0f);
            if (diag && (mk * 16 + q * 4 + r) > (qloc + nq * 16)) pv = 0.f;
            rs[nq] += pv;
            pk[r] = (bf16_t)pv;
          }
          *(bf16x4*)(&Ps[w][nq][0] + l15 * 72 + mk * 16 + q * 4) = pk;
        }
    }
    // O^T += V^T * P  (wave-private stripes; in-wave lgkmcnt ordering)
#pragma unroll
    for (int nq = 0; nq < 2; ++nq) {
      bf16x8 pb0 = *(const bf16x8*)(&Ps[w][nq][0] + l15 * 72 + q * 8);
      bf16x8 pb1 = *(const bf16x8*)(&Ps[w][nq][0] + l15 * 72 + 32 + q * 8);
      __builtin_amdgcn_s_setprio(1);
#pragma unroll
      for (int md = 0; md < 4; ++md) {
        o[md][nq] = mfma16(va0[md], pb0, o[md][nq]);
        o[md][nq] = mfma16(va1[md], pb1, o[md][nq]);
      }
      __builtin_amdgcn_s_setprio(0);
    }
  }

  // row-sum reduction across the 4 q-lane groups of each query column
#pragma unroll
  for (int nq = 0; nq < 2; ++nq) {
    rs[nq] += __shfl_xor(rs[nq], 16);
    rs[nq] += __shfl_xor(rs[nq], 32);
  }
  float inv[2] = {1.f / rs[0], 1.f / rs[1]};
#pragma unroll
  for (int md = 0; md < 4; ++md)
#pragma unroll
    for (int nq = 0; nq < 2; ++nq) {
      bf16x4 ov = {(bf16_t)(o[md][nq][0] * inv[nq]), (bf16_t)(o[md][nq][1] * inv[nq]),
                   (bf16_t)(o[md][nq][2] * inv[nq]), (bf16_t)(o[md][nq][3] * inv[nq])};
      *(bf16x4*)(AO + (size_t)(b * 2048 + qt * 64 + w * 32 + nq * 16 + l15) * 1024 +
                 h * 64 + md * 16 + q * 4) = ov;
    }
}

extern "C" void kernel_launch(void* const* d_in, const int* in_sizes, int n_in,
                              void* d_out, int out_size, void* d_ws, size_t ws_size,
                              hipStream_t stream) {
  (void)in_sizes; (void)n_in; (void)out_size; (void)ws_size;
  const int BS = 8192;  // B*S
  const float* x  = (const float*)d_in[0];
  const float* Wq = (const float*)d_in[1];
  const float* bq = (const float*)d_in[2];
  const float* Wk = (const float*)d_in[3];
  const float* bk = (const float*)d_in[4];
  const float* Wv = (const float*)d_in[5];
  const float* bv = (const float*)d_in[6];
  const float* Wo = (const float*)d_in[7];
  const float* bo = (const float*)d_in[8];
  float* out = (float*)d_out;

  bf16_t* p = (bf16_t*)d_ws;
  bf16_t* WqT  = p; p += 1024 * 1024;
  bf16_t* WkvT = p; p += 128 * 1024;   // rows 0-63 = Wk^T, 64-127 = Wv^T
  bf16_t* WoT  = p; p += 1024 * 1024;
  bf16_t* xb   = p; p += (size_t)BS * 1024;
  bf16_t* Qb   = p; p += (size_t)BS * 1024;
  bf16_t* KVb  = p; p += (size_t)BS * 128;   // cols 0-63 = K, 64-127 = V
  float*  bkv  = (float*)p; p += 256;        // 128 f32
  bf16_t* AO  = xb;   // x dead after projections
  bf16_t* VtG = WqT;  // Wq dead after Q projection

  cvt_f32_to_bf16<<<(BS * 1024 / 4 + 255) / 256, 256, 0, stream>>>(x, xb, BS * 1024);
  transpose_cvt_t<<<dim3(16, 16), 256, 0, stream>>>(Wq, WqT, 1024, 1024);
  transpose_cvt_t<<<dim3(1, 16), 256, 0, stream>>>(Wk, WkvT, 1024, 64);
  transpose_cvt_t<<<dim3(1, 16), 256, 0, stream>>>(Wv, WkvT + 64 * 1024, 1024, 64);
  transpose_cvt_t<<<dim3(16, 16), 256, 0, stream>>>(Wo, WoT, 1024, 1024);
  pack_bias_kv<<<1, 128, 0, stream>>>(bk, bv, bkv);

  gemm_nt_bias_b16<<<dim3(BS / 128, 8), 256, 0, stream>>>(xb, WqT, bq, Qb, BS, 1024, 1024);
  // fused K+V projection: one N=128 dispatch instead of two N=64
  gemm_nt_bias_b16<<<dim3(BS / 128, 1), 256, 0, stream>>>(xb, WkvT, bkv, KVb, BS, 128, 1024);

  transpose_v<<<dim3(32, 4), 256, 0, stream>>>(KVb, VtG);

  mqa_attn8<<<dim3(2048), 128, 0, stream>>>(Qb, KVb, VtG, AO);

  gemm_nt_bias_f32<<<dim3(BS / 128, 8), 256, 0, stream>>>(AO, WoT, bo, out, BS, 1024, 1024);
}

// Round 6
// 247.898 us; speedup vs baseline: 1.4195x; 1.2953x over previous
//
#include <hip/hip_runtime.h>
#include <hip/hip_bf16.h>

typedef __bf16 bf16_t;
typedef __bf16 bf16x4 __attribute__((ext_vector_type(4)));
typedef __bf16 bf16x8 __attribute__((ext_vector_type(8)));
typedef float f32x4 __attribute__((ext_vector_type(4)));

#define AS1(p) ((const __attribute__((address_space(1))) void*)(p))
#define AS3(p) ((__attribute__((address_space(3))) void*)(p))

__device__ __forceinline__ f32x4 mfma16(bf16x8 a, bf16x8 b, f32x4 c) {
  return __builtin_amdgcn_mfma_f32_16x16x32_bf16(a, b, c, 0, 0, 0);
}

// ---- fused prep: x cast + 4 weight transposes + bias pack (was 6 launches) ----
// blocks 0..255: Wq -> WqT ; 256..271: Wk -> WkvT[0:64] ; 272..287: Wv ->
// WkvT[64:128] ; 288..543: Wo -> WoT ; 544: bias pack ; 545+: x -> bf16.
__global__ void prep(const float* __restrict__ x, const float* __restrict__ Wq,
                     const float* __restrict__ Wk, const float* __restrict__ Wv,
                     const float* __restrict__ Wo, const float* __restrict__ bk,
                     const float* __restrict__ bv, bf16_t* __restrict__ xb,
                     bf16_t* __restrict__ WqT, bf16_t* __restrict__ WkvT,
                     bf16_t* __restrict__ WoT, float* __restrict__ bkv) {
  const int u = blockIdx.x;
  if (u >= 545) {  // x cast: 8192*1024 f32 -> bf16, 4/lane
    int i = ((u - 545) * 256 + threadIdx.x) * 4;
    float4 v = *(const float4*)(x + i);
    bf16x4 o = {(bf16_t)v.x, (bf16_t)v.y, (bf16_t)v.z, (bf16_t)v.w};
    *(bf16x4*)(xb + i) = o;
    return;
  }
  if (u == 544) {
    if (threadIdx.x < 128)
      bkv[threadIdx.x] = (threadIdx.x < 64) ? bk[threadIdx.x] : bv[threadIdx.x - 64];
    return;
  }
  const float* W; bf16_t* Wt; int N, bx, by;
  if (u < 256)      { W = Wq; Wt = WqT;             N = 1024; bx = u & 15;        by = u >> 4; }
  else if (u < 272) { W = Wk; Wt = WkvT;            N = 64;   bx = 0;             by = u - 256; }
  else if (u < 288) { W = Wv; Wt = WkvT + 64 * 1024; N = 64;  bx = 0;             by = u - 272; }
  else              { W = Wo; Wt = WoT;             N = 1024; bx = (u - 288) & 15; by = (u - 288) >> 4; }
  __shared__ float t[64][65];
  const int n0 = bx * 64, k0 = by * 64;
  const int tx = threadIdx.x & 63, ty = threadIdx.x >> 6;
#pragma unroll
  for (int i = 0; i < 16; ++i)
    t[ty * 16 + i][tx] = W[(size_t)(k0 + ty * 16 + i) * N + n0 + tx];
  __syncthreads();
#pragma unroll
  for (int i = 0; i < 16; ++i)
    Wt[(size_t)(n0 + ty * 16 + i) * 1024 + k0 + tx] = (bf16_t)t[tx][ty * 16 + i];
}

// C[M,N] = A[M,K] @ Bt[N,K]^T + bias ; 128x128 tile, BK=32, 4 waves.
__global__ __launch_bounds__(256, 2)
void gemm_nt_bias_b16(const bf16_t* __restrict__ A, const bf16_t* __restrict__ Bt,
                      const float* __restrict__ bias, bf16_t* __restrict__ C,
                      int M, int N, int K) {
  __shared__ __align__(16) bf16_t As[128 * 32];
  __shared__ __align__(16) bf16_t Bs[128 * 32];
  const int tid = threadIdx.x;
  const int w = tid >> 6, l = tid & 63;
  const int l15 = l & 15, q = l >> 4;
  const int m0 = blockIdx.x * 128, n0 = blockIdx.y * 128;
  const int mw = (w >> 1) * 64, nw = (w & 1) * 64;
  f32x4 acc[4][4] = {};
  const int kb = (l & 3) * 8;
  int rA[2], rB[2];
#pragma unroll
  for (int i = 0; i < 2; ++i) {
    int row = (i * 4 + w) * 16 + (l >> 2);
    rA[i] = m0 + row;
    int rb = n0 + row; if (rb >= N) rb = N - 1;
    rB[i] = rb;
  }
  for (int k0 = 0; k0 < K; k0 += 32) {
#pragma unroll
    for (int i = 0; i < 2; ++i) {
      int sg = i * 4 + w;
      __builtin_amdgcn_global_load_lds(AS1(A + (size_t)rA[i] * K + k0 + kb),
                                       AS3(As + sg * 512), 16, 0, 0);
      __builtin_amdgcn_global_load_lds(AS1(Bt + (size_t)rB[i] * K + k0 + kb),
                                       AS3(Bs + sg * 512), 16, 0, 0);
    }
    __syncthreads();
    bf16x8 af[4], bfr[4];
#pragma unroll
    for (int mi = 0; mi < 4; ++mi)
      af[mi] = *(const bf16x8*)(As + (mw + mi * 16 + l15) * 32 + q * 8);
#pragma unroll
    for (int ni = 0; ni < 4; ++ni)
      bfr[ni] = *(const bf16x8*)(Bs + (nw + ni * 16 + l15) * 32 + q * 8);
#pragma unroll
    for (int mi = 0; mi < 4; ++mi)
#pragma unroll
      for (int ni = 0; ni < 4; ++ni)
        acc[mi][ni] = mfma16(af[mi], bfr[ni], acc[mi][ni]);
    __syncthreads();
  }
#pragma unroll
  for (int ni = 0; ni < 4; ++ni) {
    int col = n0 + nw + ni * 16 + l15;
    if (col >= N) continue;
    float bv = bias[col];
#pragma unroll
    for (int mi = 0; mi < 4; ++mi)
#pragma unroll
      for (int r = 0; r < 4; ++r) {
        int row = m0 + mw + mi * 16 + q * 4 + r;
        C[(size_t)row * N + col] = (bf16_t)(acc[mi][ni][r] + bv);
      }
  }
}

// KV projection (N=128 fixed) with fused V^T side-write: removes transpose_v
// kernel + its global round-trip. Cols 0-63 = K, 64-127 = V; V also written
// transposed to VtG[(b*64+d)*2048 + s].
__global__ __launch_bounds__(256, 2)
void gemm_kv(const bf16_t* __restrict__ A, const bf16_t* __restrict__ Bt,
             const float* __restrict__ bias, bf16_t* __restrict__ C,
             bf16_t* __restrict__ VtG, int M, int K) {
  __shared__ __align__(16) bf16_t As[128 * 32];
  __shared__ __align__(16) bf16_t Bs[128 * 32];
  const int tid = threadIdx.x;
  const int w = tid >> 6, l = tid & 63;
  const int l15 = l & 15, q = l >> 4;
  const int m0 = blockIdx.x * 128;
  const int mw = (w >> 1) * 64, nw = (w & 1) * 64;
  f32x4 acc[4][4] = {};
  const int kb = (l & 3) * 8;
  int rA[2], rB[2];
#pragma unroll
  for (int i = 0; i < 2; ++i) {
    int row = (i * 4 + w) * 16 + (l >> 2);
    rA[i] = m0 + row;
    rB[i] = row;  // N=128 rows of Bt
  }
  for (int k0 = 0; k0 < K; k0 += 32) {
#pragma unroll
    for (int i = 0; i < 2; ++i) {
      int sg = i * 4 + w;
      __builtin_amdgcn_global_load_lds(AS1(A + (size_t)rA[i] * K + k0 + kb),
                                       AS3(As + sg * 512), 16, 0, 0);
      __builtin_amdgcn_global_load_lds(AS1(Bt + (size_t)rB[i] * K + k0 + kb),
                                       AS3(Bs + sg * 512), 16, 0, 0);
    }
    __syncthreads();
    bf16x8 af[4], bfr[4];
#pragma unroll
    for (int mi = 0; mi < 4; ++mi)
      af[mi] = *(const bf16x8*)(As + (mw + mi * 16 + l15) * 32 + q * 8);
#pragma unroll
    for (int ni = 0; ni < 4; ++ni)
      bfr[ni] = *(const bf16x8*)(Bs + (nw + ni * 16 + l15) * 32 + q * 8);
#pragma unroll
    for (int mi = 0; mi < 4; ++mi)
#pragma unroll
      for (int ni = 0; ni < 4; ++ni)
        acc[mi][ni] = mfma16(af[mi], bfr[ni], acc[mi][ni]);
    __syncthreads();
  }
#pragma unroll
  for (int ni = 0; ni < 4; ++ni) {
    int col = nw + ni * 16 + l15;
    float bv = bias[col];
#pragma unroll
    for (int mi = 0; mi < 4; ++mi)
#pragma unroll
      for (int r = 0; r < 4; ++r) {
        int row = m0 + mw + mi * 16 + q * 4 + r;
        bf16_t v = (bf16_t)(acc[mi][ni][r] + bv);
        C[(size_t)row * 128 + col] = v;
        if (col >= 64)
          VtG[(size_t)((row >> 11) * 64 + (col - 64)) * 2048 + (row & 2047)] = v;
      }
  }
}

__global__ __launch_bounds__(256, 2)
void gemm_nt_bias_f32(const bf16_t* __restrict__ A, const bf16_t* __restrict__ Bt,
                      const float* __restrict__ bias, float* __restrict__ C,
                      int M, int N, int K) {
  __shared__ __align__(16) bf16_t As[128 * 32];
  __shared__ __align__(16) bf16_t Bs[128 * 32];
  const int tid = threadIdx.x;
  const int w = tid >> 6, l = tid & 63;
  const int l15 = l & 15, q = l >> 4;
  const int m0 = blockIdx.x * 128, n0 = blockIdx.y * 128;
  const int mw = (w >> 1) * 64, nw = (w & 1) * 64;
  f32x4 acc[4][4] = {};
  const int kb = (l & 3) * 8;
  int rA[2], rB[2];
#pragma unroll
  for (int i = 0; i < 2; ++i) {
    int row = (i * 4 + w) * 16 + (l >> 2);
    rA[i] = m0 + row;
    int rb = n0 + row; if (rb >= N) rb = N - 1;
    rB[i] = rb;
  }
  for (int k0 = 0; k0 < K; k0 += 32) {
#pragma unroll
    for (int i = 0; i < 2; ++i) {
      int sg = i * 4 + w;
      __builtin_amdgcn_global_load_lds(AS1(A + (size_t)rA[i] * K + k0 + kb),
                                       AS3(As + sg * 512), 16, 0, 0);
      __builtin_amdgcn_global_load_lds(AS1(Bt + (size_t)rB[i] * K + k0 + kb),
                                       AS3(Bs + sg * 512), 16, 0, 0);
    }
    __syncthreads();
    bf16x8 af[4], bfr[4];
#pragma unroll
    for (int mi = 0; mi < 4; ++mi)
      af[mi] = *(const bf16x8*)(As + (mw + mi * 16 + l15) * 32 + q * 8);
#pragma unroll
    for (int ni = 0; ni < 4; ++ni)
      bfr[ni] = *(const bf16x8*)(Bs + (nw + ni * 16 + l15) * 32 + q * 8);
#pragma unroll
    for (int mi = 0; mi < 4; ++mi)
#pragma unroll
      for (int ni = 0; ni < 4; ++ni)
        acc[mi][ni] = mfma16(af[mi], bfr[ni], acc[mi][ni]);
    __syncthreads();
  }
#pragma unroll
  for (int ni = 0; ni < 4; ++ni) {
    int col = n0 + nw + ni * 16 + l15;
    if (col >= N) continue;
    float bv = bias[col];
#pragma unroll
    for (int mi = 0; mi < 4; ++mi)
#pragma unroll
      for (int r = 0; r < 4; ++r) {
        int row = m0 + mw + mi * 16 + q * 4 + r;
        C[(size_t)row * N + col] = acc[mi][ni][r] + bv;
      }
  }
}

// ---- MQA flash v9: v6 structure (best measured: 78us) + diag-peel ----
// v8 post-mortem: output-split halves per-wave arithmetic intensity while
// keeping the per-step serial chain fixed -> 2x wave-steps, net 1.8x slower.
// v6's kt-split/pairing kept. New here: (a) causal cndmask+cmp ran 64x on
// EVERY step but only matters on the diagonal tile (~6% of steps) -> peel
// kt==qt into template<bool DIAG>; (b) K read from fused KVb (stride 128).
__device__ __forceinline__ void load_q(const bf16_t* __restrict__ Qb, int b, int h,
                                       int qt, int l15, int q,
                                       bf16x8 (&qf0)[4], bf16x8 (&qf1)[4]) {
#pragma unroll
  for (int nq = 0; nq < 4; ++nq) {
    const bf16_t* qp = Qb + (size_t)(b * 2048 + qt * 64 + nq * 16 + l15) * 1024 + h * 64 + q * 8;
    qf0[nq] = *(const bf16x8*)qp;
    qf1[nq] = *(const bf16x8*)(qp + 32);
  }
}

template <bool DIAG>
__device__ __forceinline__ void attn_step(
    const bf16_t* __restrict__ kbase, const bf16_t* __restrict__ vbase, int kt,
    int l15, int q, bf16_t* __restrict__ ps,
    const bf16x8 (&qf0)[4], const bf16x8 (&qf1)[4],
    f32x4 (&o)[4][4], float (&rs)[4]) {
  const float c1 = 0.18033688f;  // log2(e)/8
  const bf16_t* kb = kbase + (size_t)kt * 64 * 128;  // K: cols 0-63 of KVb rows
  bf16x8 ka0[4], ka1[4];
#pragma unroll
  for (int mk = 0; mk < 4; ++mk) {
    const bf16_t* kr = kb + (mk * 16 + l15) * 128;
    ka0[mk] = *(const bf16x8*)(kr + q * 8);
    ka1[mk] = *(const bf16x8*)(kr + 32 + q * 8);
  }
  bf16x8 va0[4], va1[4];
#pragma unroll
  for (int md = 0; md < 4; ++md) {
    const bf16_t* vr = vbase + (size_t)(md * 16 + l15) * 2048 + kt * 64;
    va0[md] = *(const bf16x8*)(vr + q * 8);
    va1[md] = *(const bf16x8*)(vr + 32 + q * 8);
  }
  // S^T = K*Q^T in two mk-halves (bounds live s-registers)
#pragma unroll
  for (int mh = 0; mh < 2; ++mh) {
    f32x4 s2[2][4];
    __builtin_amdgcn_s_setprio(1);
#pragma unroll
    for (int mk2 = 0; mk2 < 2; ++mk2)
#pragma unroll
      for (int nq = 0; nq < 4; ++nq) {
        f32x4 t = {0.f, 0.f, 0.f, 0.f};
        t = mfma16(ka0[mh * 2 + mk2], qf0[nq], t);
        t = mfma16(ka1[mh * 2 + mk2], qf1[nq], t);
        s2[mk2][nq] = t;
      }
    __builtin_amdgcn_s_setprio(0);
#pragma unroll
    for (int nq = 0; nq < 4; ++nq)
#pragma unroll
      for (int mk2 = 0; mk2 < 2; ++mk2) {
        const int mk = mh * 2 + mk2;
        bf16x4 pk;
#pragma unroll
        for (int r = 0; r < 4; ++r) {
          float pv = __builtin_amdgcn_exp2f(s2[mk2][nq][r] * c1 - 16.0f);
          if (DIAG && (mk * 16 + q * 4 + r) > (nq * 16 + l15)) pv = 0.f;
          rs[nq] += pv;
          pk[r] = (bf16_t)pv;
        }
        *(bf16x4*)(ps + nq * 1152 + l15 * 72 + mk * 16 + q * 4) = pk;
      }
  }
  // O^T += V^T * P
#pragma unroll
  for (int nq = 0; nq < 4; ++nq) {
    bf16x8 pb0 = *(const bf16x8*)(ps + nq * 1152 + l15 * 72 + q * 8);
    bf16x8 pb1 = *(const bf16x8*)(ps + nq * 1152 + l15 * 72 + 32 + q * 8);
    __builtin_amdgcn_s_setprio(1);
#pragma unroll
    for (int md = 0; md < 4; ++md) {
      o[md][nq] = mfma16(va0[md], pb0, o[md][nq]);
      o[md][nq] = mfma16(va1[md], pb1, o[md][nq]);
    }
    __builtin_amdgcn_s_setprio(0);
  }
}

__device__ __forceinline__ void attn_finalize(bf16_t* __restrict__ AO, int b, int h,
                                              int qt, int l15, int q,
                                              f32x4 (&o)[4][4], float (&rs)[4]) {
#pragma unroll
  for (int nq = 0; nq < 4; ++nq) {
    rs[nq] += __shfl_xor(rs[nq], 16);
    rs[nq] += __shfl_xor(rs[nq], 32);
  }
  float inv[4];
#pragma unroll
  for (int nq = 0; nq < 4; ++nq) inv[nq] = 1.f / rs[nq];
#pragma unroll
  for (int md = 0; md < 4; ++md)
#pragma unroll
    for (int nq = 0; nq < 4; ++nq) {
      bf16x4 ov = {(bf16_t)(o[md][nq][0] * inv[nq]), (bf16_t)(o[md][nq][1] * inv[nq]),
                   (bf16_t)(o[md][nq][2] * inv[nq]), (bf16_t)(o[md][nq][3] * inv[nq])};
      *(bf16x4*)(AO + (size_t)(b * 2048 + qt * 64 + nq * 16 + l15) * 1024 +
                 h * 64 + md * 16 + q * 4) = ov;
    }
}

__global__ __launch_bounds__(128, 2)
void mqa_attn9(const bf16_t* __restrict__ Qb, const bf16_t* __restrict__ KVb,
               const bf16_t* __restrict__ VtG, bf16_t* __restrict__ AO) {
  __shared__ __align__(16) bf16_t Ps[2][4][16 * 72];  // 18 KB
  __shared__ __align__(16) float Oc[4096];            // 16 KB combine buffer
  __shared__ float RSc[256];                          // 1 KB
  const int u = blockIdx.x;
  const int b = u & 3;                 // one batch per XCD L2
  const int h = (u >> 2) & 15;
  const int p = (u >> 6) & 15;         // pair id; qt_h = 31-p, qt_l = p
  const int w = threadIdx.x >> 6, l = threadIdx.x & 63;
  const int l15 = l & 15, q = l >> 4;
  const int qt_h = 31 - p;
  bf16_t* ps = &Ps[w][0][0];
  const bf16_t* kbase = KVb + (size_t)b * 2048 * 128;
  const bf16_t* vbase = VtG + (size_t)b * 64 * 2048;

  bf16x8 qf0[4], qf1[4];
  f32x4 o[4][4] = {};
  float rs[4] = {0.f, 0.f, 0.f, 0.f};

  if (w == 0) {
    // first 17 steps of the heavy tile (diag included only when p==15)
    load_q(Qb, b, h, qt_h, l15, q, qf0, qf1);
    const int e = (p == 15) ? 16 : 17;
    for (int kt = 0; kt < e; ++kt)
      attn_step<false>(kbase, vbase, kt, l15, q, ps, qf0, qf1, o, rs);
    if (p == 15)
      attn_step<true>(kbase, vbase, 16, l15, q, ps, qf0, qf1, o, rs);
    __syncthreads();  // wave1's partial is in Oc/RSc
#pragma unroll
    for (int md = 0; md < 4; ++md)
#pragma unroll
      for (int nq = 0; nq < 4; ++nq)
        o[md][nq] += *(const f32x4*)&Oc[((md * 4 + nq) * 64 + l) * 4];
#pragma unroll
    for (int nq = 0; nq < 4; ++nq) rs[nq] += RSc[l * 4 + nq];
    attn_finalize(AO, b, h, qt_h, l15, q, o, rs);
  } else {
    // light tile complete (p steps + diag), written directly
    load_q(Qb, b, h, p, l15, q, qf0, qf1);
    for (int kt = 0; kt < p; ++kt)
      attn_step<false>(kbase, vbase, kt, l15, q, ps, qf0, qf1, o, rs);
    attn_step<true>(kbase, vbase, p, l15, q, ps, qf0, qf1, o, rs);
    attn_finalize(AO, b, h, p, l15, q, o, rs);
    // heavy-tile tail [17, 31-p] incl diag (empty when p==15)
#pragma unroll
    for (int md = 0; md < 4; ++md)
#pragma unroll
      for (int nq = 0; nq < 4; ++nq) o[md][nq] = f32x4{0.f, 0.f, 0.f, 0.f};
    rs[0] = rs[1] = rs[2] = rs[3] = 0.f;
    if (p < 15) {
      load_q(Qb, b, h, qt_h, l15, q, qf0, qf1);
      for (int kt = 17; kt < 31 - p; ++kt)
        attn_step<false>(kbase, vbase, kt, l15, q, ps, qf0, qf1, o, rs);
      attn_step<true>(kbase, vbase, 31 - p, l15, q, ps, qf0, qf1, o, rs);
    }
#pragma unroll
    for (int md = 0; md < 4; ++md)
#pragma unroll
      for (int nq = 0; nq < 4; ++nq)
        *(f32x4*)&Oc[((md * 4 + nq) * 64 + l) * 4] = o[md][nq];
#pragma unroll
    for (int nq = 0; nq < 4; ++nq) RSc[l * 4 + nq] = rs[nq];
    __syncthreads();  // release partial to wave0
  }
}

extern "C" void kernel_launch(void* const* d_in, const int* in_sizes, int n_in,
                              void* d_out, int out_size, void* d_ws, size_t ws_size,
                              hipStream_t stream) {
  (void)in_sizes; (void)n_in; (void)out_size; (void)ws_size;
  const int BS = 8192;  // B*S
  const float* x  = (const float*)d_in[0];
  const float* Wq = (const float*)d_in[1];
  const float* bq = (const float*)d_in[2];
  const float* Wk = (const float*)d_in[3];
  const float* bk = (const float*)d_in[4];
  const float* Wv = (const float*)d_in[5];
  const float* bv = (const float*)d_in[6];
  const float* Wo = (const float*)d_in[7];
  const float* bo = (const float*)d_in[8];
  float* out = (float*)d_out;

  bf16_t* p = (bf16_t*)d_ws;
  bf16_t* WqT  = p; p += 1024 * 1024;
  bf16_t* WkvT = p; p += 128 * 1024;   // rows 0-63 = Wk^T, 64-127 = Wv^T
  bf16_t* WoT  = p; p += 1024 * 1024;
  bf16_t* xb   = p; p += (size_t)BS * 1024;
  bf16_t* Qb   = p; p += (size_t)BS * 1024;
  bf16_t* KVb  = p; p += (size_t)BS * 128;   // cols 0-63 = K, 64-127 = V
  float*  bkv  = (float*)p; p += 256;        // 128 f32
  bf16_t* AO  = xb;   // x dead after projections
  bf16_t* VtG = WqT;  // Wq dead after Q projection

  // 5 launches total (was 11): prep, Q gemm, KV gemm (+V^T side-write),
  // attn, O gemm.
  prep<<<dim3(545 + BS * 1024 / 1024), 256, 0, stream>>>(
      x, Wq, Wk, Wv, Wo, bk, bv, xb, WqT, WkvT, WoT, bkv);

  gemm_nt_bias_b16<<<dim3(BS / 128, 8), 256, 0, stream>>>(xb, WqT, bq, Qb, BS, 1024, 1024);
  gemm_kv<<<dim3(BS / 128, 1), 256, 0, stream>>>(xb, WkvT, bkv, KVb, VtG, BS, 1024);

  mqa_attn9<<<dim3(1024), 128, 0, stream>>>(Qb, KVb, VtG, AO);

  gemm_nt_bias_f32<<<dim3(BS / 128, 8), 256, 0, stream>>>(AO, WoT, bo, out, BS, 1024, 1024);
}